// Round 1
// baseline (919.801 us; speedup 1.0000x reference)
//
#include <hip/hip_runtime.h>

#define BB   8
#define NN   4096
#define CIN  64
#define COUT 128
#define KNN  16

// ---------------------------------------------------------------------------
// Kernel 1: per-point squared norms; block 0 also zeroes the stats accumulator
// ---------------------------------------------------------------------------
__global__ __launch_bounds__(256) void sqnorm_zero_kernel(
    const float* __restrict__ x, float* __restrict__ sq, float* __restrict__ stats)
{
    int i = blockIdx.x * 256 + threadIdx.x;            // 0 .. B*N-1
    const float4* xr = (const float4*)(x + (size_t)i * CIN);
    float s0 = 0.f, s1 = 0.f, s2 = 0.f, s3 = 0.f;
#pragma unroll
    for (int j = 0; j < CIN / 4; ++j) {
        float4 v = xr[j];
        s0 = fmaf(v.x, v.x, s0);
        s1 = fmaf(v.y, v.y, s1);
        s2 = fmaf(v.z, v.z, s2);
        s3 = fmaf(v.w, v.w, s3);
    }
    sq[i] = (s0 + s1) + (s2 + s3);
    if (blockIdx.x == 0) stats[threadIdx.x] = 0.0f;    // 256 floats: sum[128], sumsq[128]
}

// ---------------------------------------------------------------------------
// Kernel 2: kNN (top-16 smallest distances, top_k tie semantics) + max-pool
// Block = 64 points of one batch; wave q scans candidate range [q*1024,(q+1)*1024)
// so candidate loads are wave-uniform (scalar loads). Register top-16 per thread,
// 4-way merge in LDS, then gather + channel-wise max.
// ---------------------------------------------------------------------------
__global__ __launch_bounds__(256) void knn_pool_kernel(
    const float* __restrict__ x, const float* __restrict__ sq,
    float* __restrict__ pooled)
{
    __shared__ float s_dist[64 * 64];   // 16 KB: x-tile staging, then candidate dists
    __shared__ int   s_idx [64 * 64];   // 16 KB: candidate indices
    __shared__ int   s_out [64 * KNN];  // 4 KB: merged neighbor indices

    int blk = blockIdx.x;
    int b   = blk >> 6;                 // 64 tiles per batch
    int n0  = (blk & 63) * 64;
    int t   = threadIdx.x;
    int p   = t & 63;                   // point within tile
    int q   = t >> 6;                   // wave id = candidate quarter

    const float* xb  = x  + (size_t)b * NN * CIN;
    const float* sqb = sq + (size_t)b * NN;

    // stage x tile (64 rows x 64 ch) into LDS, coalesced
    {
        int r  = t >> 2;
        int ch = (t & 3) * 16;
        const float4* src = (const float4*)(xb + (size_t)(n0 + r) * CIN + ch);
        float4* dst = (float4*)(s_dist + r * CIN + ch);
        dst[0] = src[0]; dst[1] = src[1]; dst[2] = src[2]; dst[3] = src[3];
    }
    __syncthreads();

    float xn[CIN];
#pragma unroll
    for (int c = 0; c < CIN; ++c) xn[c] = s_dist[p * CIN + c];
    float sqn = sqb[n0 + p];
    __syncthreads();                    // staging region free for reuse

    float best[KNN];
    int   bidx[KNN];
#pragma unroll
    for (int j = 0; j < KNN; ++j) { best[j] = 3.4e38f; bidx[j] = 0; }

    int m0 = q * (NN / 4);
    for (int mm = 0; mm < NN / 4; ++mm) {
        int m = __builtin_amdgcn_readfirstlane(m0 + mm);   // wave-uniform -> scalar loads
        const float4* xm4 = (const float4*)(xb + (size_t)m * CIN);
        float d0 = 0.f, d1 = 0.f, d2 = 0.f, d3 = 0.f;
#pragma unroll
        for (int cc = 0; cc < CIN / 4; ++cc) {
            float4 v = xm4[cc];
            d0 = fmaf(xn[4 * cc + 0], v.x, d0);
            d1 = fmaf(xn[4 * cc + 1], v.y, d1);
            d2 = fmaf(xn[4 * cc + 2], v.z, d2);
            d3 = fmaf(xn[4 * cc + 3], v.w, d3);
        }
        float dot  = (d0 + d1) + (d2 + d3);
        float dist = sqn + sqb[m] - 2.0f * dot;            // same formula as reference
        if (dist < best[KNN - 1]) {                        // strict <: equal dist keeps lower idx
            best[KNN - 1] = dist; bidx[KNN - 1] = m;
#pragma unroll
            for (int j = KNN - 1; j > 0; --j) {            // one bubble pass, strict <
                bool sw = best[j] < best[j - 1];
                float da = best[j - 1], db = best[j];
                int   ia = bidx[j - 1], ib = bidx[j];
                best[j - 1] = sw ? db : da;  best[j] = sw ? da : db;
                bidx[j - 1] = sw ? ib : ia;  bidx[j] = sw ? ia : ib;
            }
        }
    }

    // candidates to LDS: layout [cand 64][point 64] -> conflict-free
#pragma unroll
    for (int j = 0; j < KNN; ++j) {
        s_dist[(q * KNN + j) * 64 + p] = best[j];
        s_idx [(q * KNN + j) * 64 + p] = bidx[j];
    }
    __syncthreads();

    // 4-way merge of sorted 16-lists; strict < with ascending q => lower idx wins ties
    if (t < 64) {
        int p0 = 0, p1 = 0, p2 = 0, p3 = 0;
#pragma unroll 1
        for (int k = 0; k < KNN; ++k) {
            float bd  = s_dist[(0 * KNN + p0) * 64 + t]; int bq = 0;
            float d1v = s_dist[(1 * KNN + p1) * 64 + t]; if (d1v < bd) { bd = d1v; bq = 1; }
            float d2v = s_dist[(2 * KNN + p2) * 64 + t]; if (d2v < bd) { bd = d2v; bq = 2; }
            float d3v = s_dist[(3 * KNN + p3) * 64 + t]; if (d3v < bd) { bd = d3v; bq = 3; }
            int pr = (bq == 0) ? p0 : ((bq == 1) ? p1 : ((bq == 2) ? p2 : p3));
            s_out[t * KNN + k] = s_idx[(bq * KNN + pr) * 64 + t];
            if (bq == 0) ++p0; else if (bq == 1) ++p1; else if (bq == 2) ++p2; else ++p3;
        }
    }
    __syncthreads();

    // gather neighbors and max-pool: thread t -> point t>>2, 16 channels
    {
        int pp = t >> 2;
        int cg = (t & 3) * 16;
        float acc[16];
#pragma unroll
        for (int i = 0; i < 16; ++i) acc[i] = -3.4e38f;
#pragma unroll 1
        for (int k = 0; k < KNN; ++k) {
            int idx = s_out[pp * KNN + k];
            const float4* src = (const float4*)(xb + (size_t)idx * CIN + cg);
#pragma unroll
            for (int j2 = 0; j2 < 4; ++j2) {
                float4 v = src[j2];
                acc[4 * j2 + 0] = fmaxf(acc[4 * j2 + 0], v.x);
                acc[4 * j2 + 1] = fmaxf(acc[4 * j2 + 1], v.y);
                acc[4 * j2 + 2] = fmaxf(acc[4 * j2 + 2], v.z);
                acc[4 * j2 + 3] = fmaxf(acc[4 * j2 + 3], v.w);
            }
        }
        float4* dst = (float4*)(pooled + ((size_t)b * NN + n0 + pp) * CIN + cg);
#pragma unroll
        for (int j2 = 0; j2 < 4; ++j2)
            dst[j2] = make_float4(acc[4 * j2 + 0], acc[4 * j2 + 1],
                                  acc[4 * j2 + 2], acc[4 * j2 + 3]);
    }
}

// ---------------------------------------------------------------------------
// Kernel 3: y = pooled @ W^T + b  (store y), accumulate per-channel sum/sumsq
// Block = 64 rows; W[128][64] + pooled tile in LDS.
// ---------------------------------------------------------------------------
__global__ __launch_bounds__(256) void gemm_stats_kernel(
    const float* __restrict__ pooled, const float* __restrict__ W,
    const float* __restrict__ bias, float* __restrict__ y, float* __restrict__ stats)
{
    __shared__ float sW[COUT * CIN];    // 32 KB
    __shared__ float sP[64 * CIN];      // 16 KB
    __shared__ float sred[256];

    size_t r0 = (size_t)blockIdx.x * 64;
    int t = threadIdx.x;

    for (int j = t; j < COUT * CIN / 4; j += 256)
        ((float4*)sW)[j] = ((const float4*)W)[j];
    for (int j = t; j < 64 * CIN / 4; j += 256)
        ((float4*)sP)[j] = ((const float4*)(pooled + r0 * CIN))[j];
    __syncthreads();

    int c = t & 127;                    // output channel
    int h = t >> 7;                     // row-half 0/1
    float wr[CIN];
#pragma unroll
    for (int k = 0; k < CIN; ++k) wr[k] = sW[c * CIN + k];
    float bc = bias[c];

    float lsum = 0.f, lsumsq = 0.f;
    for (int i = 0; i < 32; ++i) {
        int r = h * 32 + i;             // wave-uniform -> LDS broadcast
        float a0 = 0.f, a1 = 0.f, a2 = 0.f, a3 = 0.f;
#pragma unroll
        for (int k = 0; k < CIN; k += 4) {
            a0 = fmaf(wr[k + 0], sP[r * CIN + k + 0], a0);
            a1 = fmaf(wr[k + 1], sP[r * CIN + k + 1], a1);
            a2 = fmaf(wr[k + 2], sP[r * CIN + k + 2], a2);
            a3 = fmaf(wr[k + 3], sP[r * CIN + k + 3], a3);
        }
        float v = (a0 + a1) + (a2 + a3) + bc;
        y[(r0 + r) * COUT + c] = v;
        lsum += v; lsumsq = fmaf(v, v, lsumsq);
    }

    sred[t] = lsum; __syncthreads();
    if (h == 0) atomicAdd(&stats[c], sred[c] + sred[128 + c]);
    __syncthreads();
    sred[t] = lsumsq; __syncthreads();
    if (h == 0) atomicAdd(&stats[COUT + c], sred[c] + sred[128 + c]);
}

// ---------------------------------------------------------------------------
// Kernel 4: BatchNorm (population stats) + ReLU, float4 per thread
// ---------------------------------------------------------------------------
__global__ __launch_bounds__(256) void bn_relu_kernel(
    const float* __restrict__ y, const float* __restrict__ stats,
    const float* __restrict__ gamma, const float* __restrict__ beta,
    float* __restrict__ out)
{
    int i = blockIdx.x * 256 + threadIdx.x;            // float4 index
    float4 v = ((const float4*)y)[i];
    int c = (i * 4) & (COUT - 1);
    float r[4] = { v.x, v.y, v.z, v.w };
    float o[4];
    const float invM = 1.0f / (float)(BB * NN);
#pragma unroll
    for (int j = 0; j < 4; ++j) {
        int cc = c + j;
        float mean = stats[cc] * invM;
        float var  = stats[COUT + cc] * invM - mean * mean;
        float inv  = rsqrtf(var + 1e-5f);
        float val  = (r[j] - mean) * inv * gamma[cc] + beta[cc];
        o[j] = fmaxf(val, 0.0f);
    }
    ((float4*)out)[i] = make_float4(o[0], o[1], o[2], o[3]);
}

// ---------------------------------------------------------------------------
extern "C" void kernel_launch(void* const* d_in, const int* in_sizes, int n_in,
                              void* d_out, int out_size, void* d_ws, size_t ws_size,
                              hipStream_t stream)
{
    const float* x     = (const float*)d_in[0];
    const float* W     = (const float*)d_in[1];
    const float* bias  = (const float*)d_in[2];
    const float* gamma = (const float*)d_in[3];
    const float* beta  = (const float*)d_in[4];
    float* out = (float*)d_out;

    char* ws = (char*)d_ws;
    float* sq     = (float*)(ws);                                  // 128 KB
    float* stats  = (float*)(ws + 131072);                         // 1 KB
    float* pooled = (float*)(ws + (1u << 20));                     // 8 MB
    float* y      = (float*)(ws + (1u << 20) + 8u * 1024 * 1024);  // 16 MB

    hipLaunchKernelGGL(sqnorm_zero_kernel, dim3(BB * NN / 256), dim3(256), 0, stream,
                       x, sq, stats);
    hipLaunchKernelGGL(knn_pool_kernel, dim3(BB * NN / 64), dim3(256), 0, stream,
                       x, sq, pooled);
    hipLaunchKernelGGL(gemm_stats_kernel, dim3(BB * NN / 64), dim3(256), 0, stream,
                       pooled, W, bias, y, stats);
    hipLaunchKernelGGL(bn_relu_kernel, dim3(BB * NN * COUT / (4 * 256)), dim3(256), 0, stream,
                       y, stats, gamma, beta, out);
}

// Round 2
// 651.143 us; speedup vs baseline: 1.4126x; 1.4126x over previous
//
#include <hip/hip_runtime.h>

#define BB   8
#define NN   4096
#define CIN  64
#define COUT 128
#define KNN  16

// ---------------------------------------------------------------------------
// Kernel 1: per-point squared norms; block 0 also zeroes the stats accumulator
// ---------------------------------------------------------------------------
__global__ __launch_bounds__(256) void sqnorm_zero_kernel(
    const float* __restrict__ x, float* __restrict__ sq, float* __restrict__ stats)
{
    int i = blockIdx.x * 256 + threadIdx.x;            // 0 .. B*N-1
    const float4* xr = (const float4*)(x + (size_t)i * CIN);
    float s0 = 0.f, s1 = 0.f, s2 = 0.f, s3 = 0.f;
#pragma unroll
    for (int j = 0; j < CIN / 4; ++j) {
        float4 v = xr[j];
        s0 = fmaf(v.x, v.x, s0);
        s1 = fmaf(v.y, v.y, s1);
        s2 = fmaf(v.z, v.z, s2);
        s3 = fmaf(v.w, v.w, s3);
    }
    sq[i] = (s0 + s1) + (s2 + s3);
    if (blockIdx.x == 0) stats[threadIdx.x] = 0.0f;    // 256 floats: sum[128], sumsq[128]
}

// ---------------------------------------------------------------------------
// Kernel 2a: kNN scan. Grid = 512 tiles x 4 m-quarters (2048 blocks, 5/CU by
// LDS -> ~62% occupancy cap vs 25% before). Block = 64 points; wave q scans
// m in [mq*1024 + q*256, +256) (wave-uniform -> scalar loads). Register
// top-16 per lane, 4-way in-block merge, sorted (d,idx) list per
// (point, m-quarter) written to ws.
// ---------------------------------------------------------------------------
__global__ __launch_bounds__(256) void knn_scan_kernel(
    const float* __restrict__ x, const float* __restrict__ sq,
    float* __restrict__ mrg_d, int* __restrict__ mrg_i)
{
    __shared__ float s_dist[64 * 64];   // 16 KB: x-tile staging, then candidate dists
    __shared__ int   s_idx [64 * 64];   // 16 KB: candidate indices

    int blk  = blockIdx.x;
    int tile = blk >> 2;                // 0..511
    int mq   = blk & 3;                 // m-quarter
    int b    = tile >> 6;               // batch
    int n0   = (tile & 63) * 64;
    int t    = threadIdx.x;
    int p    = t & 63;                  // point within tile
    int q    = t >> 6;                  // wave id = sub-range within quarter

    const float* xb  = x  + (size_t)b * NN * CIN;
    const float* sqb = sq + (size_t)b * NN;

    // stage x tile (64 rows x 64 ch) into LDS, coalesced
    {
        int r  = t >> 2;
        int ch = (t & 3) * 16;
        const float4* src = (const float4*)(xb + (size_t)(n0 + r) * CIN + ch);
        float4* dst = (float4*)(s_dist + r * CIN + ch);
        dst[0] = src[0]; dst[1] = src[1]; dst[2] = src[2]; dst[3] = src[3];
    }
    __syncthreads();

    float xn[CIN];
#pragma unroll
    for (int c = 0; c < CIN; ++c) xn[c] = s_dist[p * CIN + c];
    float sqn = sqb[n0 + p];
    __syncthreads();                    // staging region free for reuse

    float best[KNN];
    int   bidx[KNN];
#pragma unroll
    for (int j = 0; j < KNN; ++j) { best[j] = 3.4e38f; bidx[j] = 0; }

    int m0 = mq * 1024 + q * 256;
    for (int mm = 0; mm < 256; ++mm) {
        int m = __builtin_amdgcn_readfirstlane(m0 + mm);   // wave-uniform -> scalar loads
        const float4* xm4 = (const float4*)(xb + (size_t)m * CIN);
        float d0 = 0.f, d1 = 0.f, d2 = 0.f, d3 = 0.f;
#pragma unroll
        for (int cc = 0; cc < CIN / 4; ++cc) {
            float4 v = xm4[cc];
            d0 = fmaf(xn[4 * cc + 0], v.x, d0);
            d1 = fmaf(xn[4 * cc + 1], v.y, d1);
            d2 = fmaf(xn[4 * cc + 2], v.z, d2);
            d3 = fmaf(xn[4 * cc + 3], v.w, d3);
        }
        float dot  = (d0 + d1) + (d2 + d3);
        float dist = sqn + sqb[m] - 2.0f * dot;            // same formula as reference
        if (dist < best[KNN - 1]) {                        // strict <: equal dist keeps lower idx
            best[KNN - 1] = dist; bidx[KNN - 1] = m;
#pragma unroll
            for (int j = KNN - 1; j > 0; --j) {            // one bubble pass, strict <
                bool sw = best[j] < best[j - 1];
                float da = best[j - 1], db = best[j];
                int   ia = bidx[j - 1], ib = bidx[j];
                best[j - 1] = sw ? db : da;  best[j] = sw ? da : db;
                bidx[j - 1] = sw ? ib : ia;  bidx[j] = sw ? ia : ib;
            }
        }
    }

    // candidates to LDS: layout [cand 64][point 64] -> conflict-free
#pragma unroll
    for (int j = 0; j < KNN; ++j) {
        s_dist[(q * KNN + j) * 64 + p] = best[j];
        s_idx [(q * KNN + j) * 64 + p] = bidx[j];
    }
    __syncthreads();

    // 4-way merge of sorted 16-lists; strict < with ascending q => lower idx
    // wins ties. Write merged sorted (d,idx) list for this m-quarter to ws.
    if (t < 64) {
        size_t base = (((size_t)b * NN + n0 + t) * 4 + mq) * KNN;
        int p0 = 0, p1 = 0, p2 = 0, p3 = 0;
#pragma unroll 1
        for (int k = 0; k < KNN; ++k) {
            float bd  = s_dist[(0 * KNN + p0) * 64 + t]; int bq = 0;
            float d1v = s_dist[(1 * KNN + p1) * 64 + t]; if (d1v < bd) { bd = d1v; bq = 1; }
            float d2v = s_dist[(2 * KNN + p2) * 64 + t]; if (d2v < bd) { bd = d2v; bq = 2; }
            float d3v = s_dist[(3 * KNN + p3) * 64 + t]; if (d3v < bd) { bd = d3v; bq = 3; }
            int pr = (bq == 0) ? p0 : ((bq == 1) ? p1 : ((bq == 2) ? p2 : p3));
            mrg_d[base + k] = bd;
            mrg_i[base + k] = s_idx[(bq * KNN + pr) * 64 + t];
            if (bq == 0) ++p0; else if (bq == 1) ++p1; else if (bq == 2) ++p2; else ++p3;
        }
    }
}

// ---------------------------------------------------------------------------
// Kernel 2b: merge the 4 per-m-quarter sorted lists (ascending mq = ascending
// m, strict < keeps reference tie semantics), then gather + max-pool.
// ---------------------------------------------------------------------------
__global__ __launch_bounds__(256) void merge_gather_pool_kernel(
    const float* __restrict__ x, const float* __restrict__ mrg_d,
    const int* __restrict__ mrg_i, float* __restrict__ pooled)
{
    __shared__ int s_out[64 * KNN];     // 4 KB: final neighbor indices

    int blk = blockIdx.x;
    int b   = blk >> 6;
    int n0  = (blk & 63) * 64;
    int t   = threadIdx.x;

    const float* xb = x + (size_t)b * NN * CIN;

    if (t < 64) {
        size_t base = (((size_t)b * NN + n0 + t) * 4) * KNN;   // [4][16]
        int p0 = 0, p1 = 0, p2 = 0, p3 = 0;
#pragma unroll 1
        for (int k = 0; k < KNN; ++k) {
            float bd  = mrg_d[base + 0 * KNN + p0]; int bq = 0;
            float d1v = mrg_d[base + 1 * KNN + p1]; if (d1v < bd) { bd = d1v; bq = 1; }
            float d2v = mrg_d[base + 2 * KNN + p2]; if (d2v < bd) { bd = d2v; bq = 2; }
            float d3v = mrg_d[base + 3 * KNN + p3]; if (d3v < bd) { bd = d3v; bq = 3; }
            int pr = (bq == 0) ? p0 : ((bq == 1) ? p1 : ((bq == 2) ? p2 : p3));
            s_out[t * KNN + k] = mrg_i[base + bq * KNN + pr];
            if (bq == 0) ++p0; else if (bq == 1) ++p1; else if (bq == 2) ++p2; else ++p3;
        }
    }
    __syncthreads();

    // gather neighbors and max-pool: thread t -> point t>>2, 16 channels
    {
        int pp = t >> 2;
        int cg = (t & 3) * 16;
        float acc[16];
#pragma unroll
        for (int i = 0; i < 16; ++i) acc[i] = -3.4e38f;
#pragma unroll 1
        for (int k = 0; k < KNN; ++k) {
            int idx = s_out[pp * KNN + k];
            const float4* src = (const float4*)(xb + (size_t)idx * CIN + cg);
#pragma unroll
            for (int j2 = 0; j2 < 4; ++j2) {
                float4 v = src[j2];
                acc[4 * j2 + 0] = fmaxf(acc[4 * j2 + 0], v.x);
                acc[4 * j2 + 1] = fmaxf(acc[4 * j2 + 1], v.y);
                acc[4 * j2 + 2] = fmaxf(acc[4 * j2 + 2], v.z);
                acc[4 * j2 + 3] = fmaxf(acc[4 * j2 + 3], v.w);
            }
        }
        float4* dst = (float4*)(pooled + ((size_t)b * NN + n0 + pp) * CIN + cg);
#pragma unroll
        for (int j2 = 0; j2 < 4; ++j2)
            dst[j2] = make_float4(acc[4 * j2 + 0], acc[4 * j2 + 1],
                                  acc[4 * j2 + 2], acc[4 * j2 + 3]);
    }
}

// ---------------------------------------------------------------------------
// Kernel 3: y = pooled @ W^T + b  (store y), accumulate per-channel sum/sumsq
// ---------------------------------------------------------------------------
__global__ __launch_bounds__(256) void gemm_stats_kernel(
    const float* __restrict__ pooled, const float* __restrict__ W,
    const float* __restrict__ bias, float* __restrict__ y, float* __restrict__ stats)
{
    __shared__ float sW[COUT * CIN];    // 32 KB
    __shared__ float sP[64 * CIN];      // 16 KB
    __shared__ float sred[256];

    size_t r0 = (size_t)blockIdx.x * 64;
    int t = threadIdx.x;

    for (int j = t; j < COUT * CIN / 4; j += 256)
        ((float4*)sW)[j] = ((const float4*)W)[j];
    for (int j = t; j < 64 * CIN / 4; j += 256)
        ((float4*)sP)[j] = ((const float4*)(pooled + r0 * CIN))[j];
    __syncthreads();

    int c = t & 127;                    // output channel
    int h = t >> 7;                     // row-half 0/1
    float wr[CIN];
#pragma unroll
    for (int k = 0; k < CIN; ++k) wr[k] = sW[c * CIN + k];
    float bc = bias[c];

    float lsum = 0.f, lsumsq = 0.f;
    for (int i = 0; i < 32; ++i) {
        int r = h * 32 + i;             // wave-uniform -> LDS broadcast
        float a0 = 0.f, a1 = 0.f, a2 = 0.f, a3 = 0.f;
#pragma unroll
        for (int k = 0; k < CIN; k += 4) {
            a0 = fmaf(wr[k + 0], sP[r * CIN + k + 0], a0);
            a1 = fmaf(wr[k + 1], sP[r * CIN + k + 1], a1);
            a2 = fmaf(wr[k + 2], sP[r * CIN + k + 2], a2);
            a3 = fmaf(wr[k + 3], sP[r * CIN + k + 3], a3);
        }
        float v = (a0 + a1) + (a2 + a3) + bc;
        y[(r0 + r) * COUT + c] = v;
        lsum += v; lsumsq = fmaf(v, v, lsumsq);
    }

    sred[t] = lsum; __syncthreads();
    if (h == 0) atomicAdd(&stats[c], sred[c] + sred[128 + c]);
    __syncthreads();
    sred[t] = lsumsq; __syncthreads();
    if (h == 0) atomicAdd(&stats[COUT + c], sred[c] + sred[128 + c]);
}

// ---------------------------------------------------------------------------
// Kernel 4: BatchNorm (population stats) + ReLU, float4 per thread
// ---------------------------------------------------------------------------
__global__ __launch_bounds__(256) void bn_relu_kernel(
    const float* __restrict__ y, const float* __restrict__ stats,
    const float* __restrict__ gamma, const float* __restrict__ beta,
    float* __restrict__ out)
{
    int i = blockIdx.x * 256 + threadIdx.x;            // float4 index
    float4 v = ((const float4*)y)[i];
    int c = (i * 4) & (COUT - 1);
    float r[4] = { v.x, v.y, v.z, v.w };
    float o[4];
    const float invM = 1.0f / (float)(BB * NN);
#pragma unroll
    for (int j = 0; j < 4; ++j) {
        int cc = c + j;
        float mean = stats[cc] * invM;
        float var  = stats[COUT + cc] * invM - mean * mean;
        float inv  = rsqrtf(var + 1e-5f);
        float val  = (r[j] - mean) * inv * gamma[cc] + beta[cc];
        o[j] = fmaxf(val, 0.0f);
    }
    ((float4*)out)[i] = make_float4(o[0], o[1], o[2], o[3]);
}

// ---------------------------------------------------------------------------
// ws layout (25 MB total, same footprint as the passing R1 kernel):
//   [0, 128K)        sq
//   [128K, 129K)     stats (sum[128], sumsq[128])
//   [1M, 9M)         mrg_d   \ consumed by kernel 2b, then
//   [9M, 17M)        mrg_i   / y ([1M,17M)) aliases over them (safe: sequential)
//   [17M, 25M)       pooled
// ---------------------------------------------------------------------------
extern "C" void kernel_launch(void* const* d_in, const int* in_sizes, int n_in,
                              void* d_out, int out_size, void* d_ws, size_t ws_size,
                              hipStream_t stream)
{
    const float* x     = (const float*)d_in[0];
    const float* W     = (const float*)d_in[1];
    const float* bias  = (const float*)d_in[2];
    const float* gamma = (const float*)d_in[3];
    const float* beta  = (const float*)d_in[4];
    float* out = (float*)d_out;

    char* ws = (char*)d_ws;
    float* sq     = (float*)(ws);
    float* stats  = (float*)(ws + 131072);
    float* mrg_d  = (float*)(ws + (1u << 20));
    int*   mrg_i  = (int*)  (ws + (1u << 20) + 8u * 1024 * 1024);
    float* y      = (float*)(ws + (1u << 20));                      // aliases mrg (after 2b)
    float* pooled = (float*)(ws + (1u << 20) + 16u * 1024 * 1024);

    hipLaunchKernelGGL(sqnorm_zero_kernel, dim3(BB * NN / 256), dim3(256), 0, stream,
                       x, sq, stats);
    hipLaunchKernelGGL(knn_scan_kernel, dim3(BB * NN / 64 * 4), dim3(256), 0, stream,
                       x, sq, mrg_d, mrg_i);
    hipLaunchKernelGGL(merge_gather_pool_kernel, dim3(BB * NN / 64), dim3(256), 0, stream,
                       x, mrg_d, mrg_i, pooled);
    hipLaunchKernelGGL(gemm_stats_kernel, dim3(BB * NN / 64), dim3(256), 0, stream,
                       pooled, W, bias, y, stats);
    hipLaunchKernelGGL(bn_relu_kernel, dim3(BB * NN * COUT / (4 * 256)), dim3(256), 0, stream,
                       y, stats, gamma, beta, out);
}

// Round 3
// 570.686 us; speedup vs baseline: 1.6117x; 1.1410x over previous
//
#include <hip/hip_runtime.h>

#define BB   8
#define NN   4096
#define CIN  64
#define COUT 128
#define KNN  16
#define NSUB 12                       // approx top-12 per sublist, 8 sublists/point

typedef _Float16 half8 __attribute__((ext_vector_type(8)));
typedef _Float16 half4v __attribute__((ext_vector_type(4)));
typedef float f32x4 __attribute__((ext_vector_type(4)));

// ---------------------------------------------------------------------------
// Kernel 1: per-point squared norms; block 0 also zeroes the stats accumulator
// ---------------------------------------------------------------------------
__global__ __launch_bounds__(256) void sqnorm_zero_kernel(
    const float* __restrict__ x, float* __restrict__ sq, float* __restrict__ stats)
{
    int i = blockIdx.x * 256 + threadIdx.x;            // 0 .. B*N-1
    const float4* xr = (const float4*)(x + (size_t)i * CIN);
    float s0 = 0.f, s1 = 0.f, s2 = 0.f, s3 = 0.f;
#pragma unroll
    for (int j = 0; j < CIN / 4; ++j) {
        float4 v = xr[j];
        s0 = fmaf(v.x, v.x, s0);
        s1 = fmaf(v.y, v.y, s1);
        s2 = fmaf(v.z, v.z, s2);
        s3 = fmaf(v.w, v.w, s3);
    }
    sq[i] = (s0 + s1) + (s2 + s3);
    if (blockIdx.x == 0) stats[threadIdx.x] = 0.0f;    // 256 floats: sum[128], sumsq[128]
}

// ---------------------------------------------------------------------------
// Kernel 2: fp32 -> fp16 copy of x (for MFMA distance computation)
// ---------------------------------------------------------------------------
__global__ __launch_bounds__(256) void prep_half_kernel(
    const float* __restrict__ x, _Float16* __restrict__ xh)
{
    int i = blockIdx.x * 256 + threadIdx.x;            // float4 index
    float4 v = ((const float4*)x)[i];
    half4v h;
    h[0] = (_Float16)v.x; h[1] = (_Float16)v.y;
    h[2] = (_Float16)v.z; h[3] = (_Float16)v.w;
    ((half4v*)xh)[i] = h;
}

// ---------------------------------------------------------------------------
// Kernel 3: MFMA kNN scan. Grid = 512 tiles x 2 candidate-halves.
// Block = 64 query points, 256 threads (4 waves). Per 64-candidate chunk:
//   stage candidate fp16 rows -> LDS (granule-transposed), MFMA 64x64 dots,
//   epilogue dist = sqn + sqm - 2*dot -> LDS tile (stride 65),
//   selection: thread (p = t&63, q = t>>6) keeps approx top-12 over its
//   16-col strip. Output: per (point, half, q) 12 candidate ids (u16).
// Exactness is restored by the rescue kernel (top-16 set ⊆ 8x12 union).
// ---------------------------------------------------------------------------
__global__ __launch_bounds__(256) void knn_scan_mfma_kernel(
    const _Float16* __restrict__ xh, const float* __restrict__ sq,
    unsigned short* __restrict__ sub_i)
{
    __shared__ _Float16 sBT[8][64][8];   // 8 KB, [k-granule][cand][8 halfs]
    __shared__ float    s_dist[64 * 65]; // 16.25 KB, [col][row] stride 65
    __shared__ float    s_sqn[64];
    __shared__ float    s_sqm[64];

    int blk  = blockIdx.x;
    int tile = blk >> 1;                 // 0..511
    int half = blk & 1;                  // candidate half (2048 each)
    int b    = tile >> 6;
    int n0   = (tile & 63) * 64;
    int t    = threadIdx.x;
    int l    = t & 63;                   // lane
    int w    = t >> 6;                   // wave id -> row strip 16w..16w+15
    int quad = (l >> 4);                 // 0..3
    int c16  = l & 15;

    const _Float16* xhb = xh + (size_t)b * NN * CIN;
    const float*    sqb = sq + (size_t)b * NN;

    if (t < 64) s_sqn[t] = sqb[n0 + t];

    // A fragments (query rows), loaded once from global in frag layout:
    // A[m = 16w + (l&15)][k = s*32 + quad*8 + j]
    int row_a = n0 + 16 * w + c16;
    half8 afrag0 = *(const half8*)(xhb + (size_t)row_a * CIN + 0 * 32 + quad * 8);
    half8 afrag1 = *(const half8*)(xhb + (size_t)row_a * CIN + 1 * 32 + quad * 8);

    // persistent approx top-12 (dist, idx) per thread
    float best[NSUB];
    int   bidx[NSUB];
#pragma unroll
    for (int j = 0; j < NSUB; ++j) { best[j] = 3.4e38f; bidx[j] = 0; }

    int p = l;                           // selection: point index
    int q = w;                           // selection: col-strip id

    for (int c = 0; c < 32; ++c) {       // 32 chunks of 64 candidates
        int cbase = half * 2048 + c * 64;

        // stage candidate tile (64 rows x 64 halfs) granule-transposed
#pragma unroll
        for (int r = 0; r < 2; ++r) {
            int f = r * 256 + t;         // 16B-granule id, 0..511
            int cand = f >> 3;
            int g    = f & 7;
            *(half8*)&sBT[g][cand][0] =
                *(const half8*)(xhb + (size_t)(cbase + cand) * CIN + g * 8);
        }
        if (t < 64) s_sqm[t] = sqb[cbase + t];
        __syncthreads();

        // MFMA: wave w computes rows [16w,16w+16) x all 64 cols (4 subtiles)
        f32x4 acc[4];
#pragma unroll
        for (int n = 0; n < 4; ++n) { acc[n] = (f32x4){0.f, 0.f, 0.f, 0.f}; }
#pragma unroll
        for (int n = 0; n < 4; ++n) {
            half8 b0 = *(const half8*)&sBT[0 * 4 + quad][16 * n + c16][0];
            half8 b1 = *(const half8*)&sBT[1 * 4 + quad][16 * n + c16][0];
            acc[n] = __builtin_amdgcn_mfma_f32_16x16x32_f16(afrag0, b0, acc[n], 0, 0, 0);
            acc[n] = __builtin_amdgcn_mfma_f32_16x16x32_f16(afrag1, b1, acc[n], 0, 0, 0);
        }

        // epilogue: dist = sqn + sqm - 2*dot, clamp >= 0, write [col][row]
#pragma unroll
        for (int n = 0; n < 4; ++n) {
            int col = 16 * n + c16;
            float sm = s_sqm[col];
#pragma unroll
            for (int r = 0; r < 4; ++r) {
                int row = 16 * w + quad * 4 + r;
                float d = fmaxf(s_sqn[row] + sm - 2.0f * acc[n][r], 0.0f);
                s_dist[col * 65 + row] = d;
            }
        }
        __syncthreads();

        // selection: thread (p, q) scans cols q*16..q*16+15 of this chunk
#pragma unroll 1
        for (int j = 0; j < 16; ++j) {
            float d = s_dist[(q * 16 + j) * 65 + p];
            if (d < best[NSUB - 1]) {
                best[NSUB - 1] = d;
                bidx[NSUB - 1] = cbase + q * 16 + j;
#pragma unroll
                for (int s = NSUB - 1; s > 0; --s) {
                    bool sw = best[s] < best[s - 1];
                    float da = best[s - 1], db = best[s];
                    int   ia = bidx[s - 1], ib = bidx[s];
                    best[s - 1] = sw ? db : da;  best[s] = sw ? da : db;
                    bidx[s - 1] = sw ? ib : ia;  bidx[s] = sw ? ia : ib;
                }
            }
        }
        __syncthreads();                 // protect s_dist/sBT before next chunk
    }

    // write sublist ids: [point][half*4+q][12]
    size_t base = (((size_t)b * NN + n0 + p) * 8 + half * 4 + q) * NSUB;
#pragma unroll
    for (int j = 0; j < NSUB; ++j)
        sub_i[base + j] = (unsigned short)bidx[j];
}

// ---------------------------------------------------------------------------
// Kernel 4: rescue — exact fp32 top-16 (set) from the 96 approx candidates.
// One thread per point.
// ---------------------------------------------------------------------------
__global__ __launch_bounds__(256) void rescue_kernel(
    const float* __restrict__ x, const float* __restrict__ sq,
    const unsigned short* __restrict__ sub_i, unsigned short* __restrict__ fin)
{
    int gp = blockIdx.x * 256 + threadIdx.x;           // global point
    int b  = gp >> 12;
    const float* xb  = x  + (size_t)b * NN * CIN;
    const float* sqb = sq + (size_t)b * NN;

    float xn[CIN];
    const float4* xr = (const float4*)(x + (size_t)gp * CIN);
#pragma unroll
    for (int j = 0; j < CIN / 4; ++j) {
        float4 v = xr[j];
        xn[4 * j + 0] = v.x; xn[4 * j + 1] = v.y;
        xn[4 * j + 2] = v.z; xn[4 * j + 3] = v.w;
    }
    float sqn = sqb[gp & (NN - 1)];

    float best[KNN];
    int   bidx[KNN];
#pragma unroll
    for (int j = 0; j < KNN; ++j) { best[j] = 3.4e38f; bidx[j] = 0; }

    const unsigned short* sl = sub_i + (size_t)gp * 8 * NSUB;
#pragma unroll 1
    for (int j = 0; j < 8 * NSUB; ++j) {
        int m = sl[j];
        const float4* xm4 = (const float4*)(xb + (size_t)m * CIN);
        float d0 = 0.f, d1 = 0.f, d2 = 0.f, d3 = 0.f;
#pragma unroll
        for (int cc = 0; cc < CIN / 4; ++cc) {
            float4 v = xm4[cc];
            d0 = fmaf(xn[4 * cc + 0], v.x, d0);
            d1 = fmaf(xn[4 * cc + 1], v.y, d1);
            d2 = fmaf(xn[4 * cc + 2], v.z, d2);
            d3 = fmaf(xn[4 * cc + 3], v.w, d3);
        }
        float d = sqn + sqb[m] - 2.0f * ((d0 + d1) + (d2 + d3));
        if (d < best[KNN - 1]) {
            best[KNN - 1] = d; bidx[KNN - 1] = m;
#pragma unroll
            for (int s = KNN - 1; s > 0; --s) {
                bool sw = best[s] < best[s - 1];
                float da = best[s - 1], db = best[s];
                int   ia = bidx[s - 1], ib = bidx[s];
                best[s - 1] = sw ? db : da;  best[s] = sw ? da : db;
                bidx[s - 1] = sw ? ib : ia;  bidx[s] = sw ? ia : ib;
            }
        }
    }
#pragma unroll
    for (int k = 0; k < KNN; ++k)
        fin[(size_t)gp * KNN + k] = (unsigned short)bidx[k];
}

// ---------------------------------------------------------------------------
// Kernel 5: gather final neighbors + max-pool. 4 threads/point, 16 ch each.
// ---------------------------------------------------------------------------
__global__ __launch_bounds__(256) void gather_pool_kernel(
    const float* __restrict__ x, const unsigned short* __restrict__ fin,
    float* __restrict__ pooled)
{
    int blk = blockIdx.x;
    int b   = blk >> 6;
    int n0  = (blk & 63) * 64;
    int t   = threadIdx.x;
    const float* xb = x + (size_t)b * NN * CIN;

    int pp = t >> 2;
    int cg = (t & 3) * 16;
    size_t gp = (size_t)b * NN + n0 + pp;
    float acc[16];
#pragma unroll
    for (int i = 0; i < 16; ++i) acc[i] = -3.4e38f;
#pragma unroll 1
    for (int k = 0; k < KNN; ++k) {
        int idx = fin[gp * KNN + k];
        const float4* src = (const float4*)(xb + (size_t)idx * CIN + cg);
#pragma unroll
        for (int j2 = 0; j2 < 4; ++j2) {
            float4 v = src[j2];
            acc[4 * j2 + 0] = fmaxf(acc[4 * j2 + 0], v.x);
            acc[4 * j2 + 1] = fmaxf(acc[4 * j2 + 1], v.y);
            acc[4 * j2 + 2] = fmaxf(acc[4 * j2 + 2], v.z);
            acc[4 * j2 + 3] = fmaxf(acc[4 * j2 + 3], v.w);
        }
    }
    float4* dst = (float4*)(pooled + gp * CIN + cg);
#pragma unroll
    for (int j2 = 0; j2 < 4; ++j2)
        dst[j2] = make_float4(acc[4 * j2 + 0], acc[4 * j2 + 1],
                              acc[4 * j2 + 2], acc[4 * j2 + 3]);
}

// ---------------------------------------------------------------------------
// Kernel 6: y = pooled @ W^T + b  (store y), accumulate per-channel sum/sumsq
// ---------------------------------------------------------------------------
__global__ __launch_bounds__(256) void gemm_stats_kernel(
    const float* __restrict__ pooled, const float* __restrict__ W,
    const float* __restrict__ bias, float* __restrict__ y, float* __restrict__ stats)
{
    __shared__ float sW[COUT * CIN];    // 32 KB
    __shared__ float sP[64 * CIN];      // 16 KB
    __shared__ float sred[256];

    size_t r0 = (size_t)blockIdx.x * 64;
    int t = threadIdx.x;

    for (int j = t; j < COUT * CIN / 4; j += 256)
        ((float4*)sW)[j] = ((const float4*)W)[j];
    for (int j = t; j < 64 * CIN / 4; j += 256)
        ((float4*)sP)[j] = ((const float4*)(pooled + r0 * CIN))[j];
    __syncthreads();

    int c = t & 127;                    // output channel
    int h = t >> 7;                     // row-half 0/1
    float wr[CIN];
#pragma unroll
    for (int k = 0; k < CIN; ++k) wr[k] = sW[c * CIN + k];
    float bc = bias[c];

    float lsum = 0.f, lsumsq = 0.f;
    for (int i = 0; i < 32; ++i) {
        int r = h * 32 + i;             // wave-uniform -> LDS broadcast
        float a0 = 0.f, a1 = 0.f, a2 = 0.f, a3 = 0.f;
#pragma unroll
        for (int k = 0; k < CIN; k += 4) {
            a0 = fmaf(wr[k + 0], sP[r * CIN + k + 0], a0);
            a1 = fmaf(wr[k + 1], sP[r * CIN + k + 1], a1);
            a2 = fmaf(wr[k + 2], sP[r * CIN + k + 2], a2);
            a3 = fmaf(wr[k + 3], sP[r * CIN + k + 3], a3);
        }
        float v = (a0 + a1) + (a2 + a3) + bc;
        y[(r0 + r) * COUT + c] = v;
        lsum += v; lsumsq = fmaf(v, v, lsumsq);
    }

    sred[t] = lsum; __syncthreads();
    if (h == 0) atomicAdd(&stats[c], sred[c] + sred[128 + c]);
    __syncthreads();
    sred[t] = lsumsq; __syncthreads();
    if (h == 0) atomicAdd(&stats[COUT + c], sred[c] + sred[128 + c]);
}

// ---------------------------------------------------------------------------
// Kernel 7: BatchNorm (population stats) + ReLU, float4 per thread
// ---------------------------------------------------------------------------
__global__ __launch_bounds__(256) void bn_relu_kernel(
    const float* __restrict__ y, const float* __restrict__ stats,
    const float* __restrict__ gamma, const float* __restrict__ beta,
    float* __restrict__ out)
{
    int i = blockIdx.x * 256 + threadIdx.x;            // float4 index
    float4 v = ((const float4*)y)[i];
    int c = (i * 4) & (COUT - 1);
    float r[4] = { v.x, v.y, v.z, v.w };
    float o[4];
    const float invM = 1.0f / (float)(BB * NN);
#pragma unroll
    for (int j = 0; j < 4; ++j) {
        int cc = c + j;
        float mean = stats[cc] * invM;
        float var  = stats[COUT + cc] * invM - mean * mean;
        float inv  = rsqrtf(var + 1e-5f);
        float val  = (r[j] - mean) * inv * gamma[cc] + beta[cc];
        o[j] = fmaxf(val, 0.0f);
    }
    ((float4*)out)[i] = make_float4(o[0], o[1], o[2], o[3]);
}

// ---------------------------------------------------------------------------
// ws layout (<= 24.25 MiB; 25 MiB known-safe from R1/R2):
//   [0, 128K)              sq (fp32, 32768)
//   [128K, 129K)           stats (sum[128], sumsq[128])
//   [256K, 4.25M)          xh (fp16, B*N*64 = 4 MB)
//   [4.25M, 10.25M)        sub_i (u16, 32768 x 96 = 6 MB)
//   [10.25M, 11.25M)       fin (u16, 32768 x 16 = 1 MB)
//   [256K, 16.25M)         y (fp32, 16 MB) — aliases xh/sub_i/fin (consumed)
//   [16.25M, 24.25M)       pooled (fp32, 8 MB)
// ---------------------------------------------------------------------------
extern "C" void kernel_launch(void* const* d_in, const int* in_sizes, int n_in,
                              void* d_out, int out_size, void* d_ws, size_t ws_size,
                              hipStream_t stream)
{
    const float* x     = (const float*)d_in[0];
    const float* W     = (const float*)d_in[1];
    const float* bias  = (const float*)d_in[2];
    const float* gamma = (const float*)d_in[3];
    const float* beta  = (const float*)d_in[4];
    float* out = (float*)d_out;

    char* ws = (char*)d_ws;
    float*          sq     = (float*)(ws);
    float*          stats  = (float*)(ws + 131072);
    _Float16*       xh     = (_Float16*)(ws + 262144);
    unsigned short* sub_i  = (unsigned short*)(ws + 262144 + 4u * 1024 * 1024);
    unsigned short* fin    = (unsigned short*)(ws + 262144 + 10u * 1024 * 1024);
    float*          y      = (float*)(ws + 262144);
    float*          pooled = (float*)(ws + 262144 + 16u * 1024 * 1024);

    hipLaunchKernelGGL(sqnorm_zero_kernel, dim3(BB * NN / 256), dim3(256), 0, stream,
                       x, sq, stats);
    hipLaunchKernelGGL(prep_half_kernel, dim3(BB * NN * CIN / 4 / 256), dim3(256), 0, stream,
                       x, xh);
    hipLaunchKernelGGL(knn_scan_mfma_kernel, dim3(BB * NN / 64 * 2), dim3(256), 0, stream,
                       xh, sq, sub_i);
    hipLaunchKernelGGL(rescue_kernel, dim3(BB * NN / 256), dim3(256), 0, stream,
                       x, sq, sub_i, fin);
    hipLaunchKernelGGL(gather_pool_kernel, dim3(BB * NN / 64), dim3(256), 0, stream,
                       x, fin, pooled);
    hipLaunchKernelGGL(gemm_stats_kernel, dim3(BB * NN / 64), dim3(256), 0, stream,
                       pooled, W, bias, y, stats);
    hipLaunchKernelGGL(bn_relu_kernel, dim3(BB * NN * COUT / (4 * 256)), dim3(256), 0, stream,
                       y, stats, gamma, beta, out);
}

// Round 4
// 358.001 us; speedup vs baseline: 2.5693x; 1.5941x over previous
//
#include <hip/hip_runtime.h>

#define BB   8
#define NN   4096
#define CIN  64
#define COUT 128
#define KNN  16
#define NSUB 12                       // approx top-12 per sublist, 8 sublists/point

typedef _Float16 half8 __attribute__((ext_vector_type(8)));
typedef float f32x4 __attribute__((ext_vector_type(4)));
typedef unsigned short u16x8 __attribute__((ext_vector_type(8)));

// ---------------------------------------------------------------------------
// Kernel 1: fused per-point squared norm + fp32->fp16 conversion; block 0
// zeroes the BN stats accumulator. One thread per point.
// ---------------------------------------------------------------------------
__global__ __launch_bounds__(256) void prep_kernel(
    const float* __restrict__ x, float* __restrict__ sq,
    _Float16* __restrict__ xh, float* __restrict__ stats)
{
    int i = blockIdx.x * 256 + threadIdx.x;            // point id
    const float4* xr = (const float4*)(x + (size_t)i * CIN);
    half8* xw = (half8*)(xh + (size_t)i * CIN);
    float s0 = 0.f, s1 = 0.f;
#pragma unroll
    for (int j = 0; j < 8; ++j) {
        float4 a = xr[2 * j], b = xr[2 * j + 1];
        s0 = fmaf(a.x, a.x, s0); s0 = fmaf(a.y, a.y, s0);
        s0 = fmaf(a.z, a.z, s0); s0 = fmaf(a.w, a.w, s0);
        s1 = fmaf(b.x, b.x, s1); s1 = fmaf(b.y, b.y, s1);
        s1 = fmaf(b.z, b.z, s1); s1 = fmaf(b.w, b.w, s1);
        half8 h;
        h[0] = (_Float16)a.x; h[1] = (_Float16)a.y;
        h[2] = (_Float16)a.z; h[3] = (_Float16)a.w;
        h[4] = (_Float16)b.x; h[5] = (_Float16)b.y;
        h[6] = (_Float16)b.z; h[7] = (_Float16)b.w;
        xw[j] = h;
    }
    sq[i] = s0 + s1;
    if (blockIdx.x == 0) stats[threadIdx.x] = 0.0f;    // sum[128], sumsq[128]
}

// ---------------------------------------------------------------------------
// Kernel 2: MFMA kNN scan with packed-key selection.
// Grid = 512 tiles x 2 candidate-halves. Block = 64 query points, 4 waves.
// Per 64-candidate chunk: stage fp16 candidates (granule-transposed) -> MFMA
// 64x64 dots -> epilogue packs key = (dist_bits & ~0xFFF) | candidate_id into
// transposed LDS tile [point][col] (stride 68: b128-readable, bank-uniform).
// Selection: thread (p=t&63, q=t>>6) keeps approx top-12 keys over its 16-col
// strip via unconditional 12-stage min/max compare-exchange (2 instr/stage).
// Output: 12 candidate ids (u16) per (point, half, q). Exactness restored by
// rescue_pool (exact fp32 re-rank of the 8x12 union).
// ---------------------------------------------------------------------------
__global__ __launch_bounds__(256) void knn_scan_mfma_kernel(
    const _Float16* __restrict__ xh, const float* __restrict__ sq,
    unsigned short* __restrict__ sub_i)
{
    __shared__ _Float16 sBT[8][64][8];   // 8 KB, [k-granule][cand][8 halfs]
    __shared__ unsigned s_key[64][68];   // 17 KB, [point][col], stride 68
    __shared__ float    s_sqn[64];
    __shared__ float    s_sqm[64];

    int blk  = blockIdx.x;
    int tile = blk >> 1;                 // 0..511
    int half = blk & 1;                  // candidate half (2048 each)
    int b    = tile >> 6;
    int n0   = (tile & 63) * 64;
    int t    = threadIdx.x;
    int l    = t & 63;                   // lane
    int w    = t >> 6;                   // wave id -> row strip 16w..16w+15
    int quad = (l >> 4);                 // 0..3
    int c16  = l & 15;

    const _Float16* xhb = xh + (size_t)b * NN * CIN;
    const float*    sqb = sq + (size_t)b * NN;

    if (t < 64) s_sqn[t] = sqb[n0 + t];

    // A fragments (query rows): A[m = 16w + c16][k = s*32 + quad*8 + j]
    int row_a = n0 + 16 * w + c16;
    half8 afrag0 = *(const half8*)(xhb + (size_t)row_a * CIN + 0 * 32 + quad * 8);
    half8 afrag1 = *(const half8*)(xhb + (size_t)row_a * CIN + 1 * 32 + quad * 8);

    // persistent approx top-12 packed keys, ascending
    unsigned best[NSUB];
#pragma unroll
    for (int j = 0; j < NSUB; ++j) best[j] = 0xFFFFFFFFu;

    int p = l;                           // selection: point index
    int q = w;                           // selection: col-strip id

    for (int c = 0; c < 32; ++c) {       // 32 chunks of 64 candidates
        int cbase = half * 2048 + c * 64;

        // stage candidate tile (64 rows x 64 halfs) granule-transposed
#pragma unroll
        for (int r = 0; r < 2; ++r) {
            int f = r * 256 + t;         // 16B-granule id, 0..511
            int cand = f >> 3;
            int g    = f & 7;
            *(half8*)&sBT[g][cand][0] =
                *(const half8*)(xhb + (size_t)(cbase + cand) * CIN + g * 8);
        }
        if (t < 64) s_sqm[t] = sqb[cbase + t];
        __syncthreads();

        // MFMA: wave w computes rows [16w,16w+16) x all 64 cols (4 subtiles)
        f32x4 acc[4];
#pragma unroll
        for (int n = 0; n < 4; ++n) { acc[n] = (f32x4){0.f, 0.f, 0.f, 0.f}; }
#pragma unroll
        for (int n = 0; n < 4; ++n) {
            half8 b0 = *(const half8*)&sBT[0 * 4 + quad][16 * n + c16][0];
            half8 b1 = *(const half8*)&sBT[1 * 4 + quad][16 * n + c16][0];
            acc[n] = __builtin_amdgcn_mfma_f32_16x16x32_f16(afrag0, b0, acc[n], 0, 0, 0);
            acc[n] = __builtin_amdgcn_mfma_f32_16x16x32_f16(afrag1, b1, acc[n], 0, 0, 0);
        }

        // epilogue: dist = max(sqn + sqm - 2*dot, 0); pack key; write [row][col]
        // (2-way bank aliasing only -> free)
#pragma unroll
        for (int n = 0; n < 4; ++n) {
            int col = 16 * n + c16;
            float sm = s_sqm[col];
            unsigned id = (unsigned)(cbase + col);
#pragma unroll
            for (int r = 0; r < 4; ++r) {
                int row = 16 * w + quad * 4 + r;
                float d = fmaxf(s_sqn[row] + sm - 2.0f * acc[n][r], 0.0f);
                s_key[row][col] = (__float_as_uint(d) & 0xFFFFF000u) | id;
            }
        }
        __syncthreads();

        // selection: thread (p, q) scans cols q*16..q*16+15, b128 key reads,
        // unconditional compare-exchange insert (2 instr/stage)
#pragma unroll
        for (int j = 0; j < 4; ++j) {
            uint4 kv = *(const uint4*)&s_key[p][q * 16 + 4 * j];
            unsigned kk[4] = { kv.x, kv.y, kv.z, kv.w };
#pragma unroll
            for (int e = 0; e < 4; ++e) {
                unsigned cur = kk[e];
#pragma unroll
                for (int s = 0; s < NSUB; ++s) {
                    unsigned lo = min(best[s], cur);
                    unsigned hi = max(best[s], cur);
                    best[s] = lo; cur = hi;
                }
            }
        }
        __syncthreads();                 // protect s_key/sBT before next chunk
    }

    // write sublist ids: [point][half*4+q][12]
    size_t base = (((size_t)b * NN + n0 + p) * 8 + half * 4 + q) * NSUB;
#pragma unroll
    for (int j = 0; j < NSUB; ++j)
        sub_i[base + j] = (unsigned short)(best[j] & 0xFFFu);
}

// ---------------------------------------------------------------------------
// Kernel 3: fused rescue + gather + max-pool. Block = 64 points, 4 threads
// per point (thread (p = t&63, sub = t>>6) handles 24 of the 96 candidates).
// Exact fp32 dists; 64-bit key = (sign-fixed dist_bits)<<32 | id gives exact
// reference ordering incl. smaller-index-wins ties. Per-thread sorted top-16
// via CE chain, 4-way LDS merge, then gather rows (L2-hot) and max-pool.
// ---------------------------------------------------------------------------
__global__ __launch_bounds__(256) void rescue_pool_kernel(
    const float* __restrict__ x, const float* __restrict__ sq,
    const unsigned short* __restrict__ sub_i, float* __restrict__ pooled)
{
    __shared__ unsigned long long s_keys[4][64][17];   // 34 KB (pad 17: bank-min)
    __shared__ int s_out[64][KNN];                     // 4 KB

    int blk = blockIdx.x;
    int b   = blk >> 6;
    int n0  = (blk & 63) * 64;
    int t   = threadIdx.x;
    int p   = t & 63;
    int sub = t >> 6;
    const float* xb  = x  + (size_t)b * NN * CIN;
    const float* sqb = sq + (size_t)b * NN;
    size_t gp = (size_t)b * NN + n0 + p;

    // query row in registers
    float xn[CIN];
    {
        const float4* xr = (const float4*)(xb + (size_t)(n0 + p) * CIN);
#pragma unroll
        for (int j = 0; j < CIN / 4; ++j) {
            float4 v = xr[j];
            xn[4 * j + 0] = v.x; xn[4 * j + 1] = v.y;
            xn[4 * j + 2] = v.z; xn[4 * j + 3] = v.w;
        }
    }
    float sqn = sqb[n0 + p];

    // 24 candidate ids (3 x 16B loads)
    unsigned short ids[24];
    {
        const u16x8* idp = (const u16x8*)(sub_i + gp * 96 + sub * 24);
        u16x8 i0 = idp[0], i1 = idp[1], i2 = idp[2];
#pragma unroll
        for (int j = 0; j < 8; ++j) {
            ids[j] = i0[j]; ids[8 + j] = i1[j]; ids[16 + j] = i2[j];
        }
    }

    unsigned long long best[KNN];
#pragma unroll
    for (int j = 0; j < KNN; ++j) best[j] = ~0ULL;

#pragma unroll 2
    for (int c = 0; c < 24; ++c) {
        int m = ids[c];
        const float4* xm4 = (const float4*)(xb + (size_t)m * CIN);
        float d0 = 0.f, d1 = 0.f, d2 = 0.f, d3 = 0.f;
#pragma unroll
        for (int cc = 0; cc < CIN / 4; ++cc) {
            float4 v = xm4[cc];
            d0 = fmaf(xn[4 * cc + 0], v.x, d0);
            d1 = fmaf(xn[4 * cc + 1], v.y, d1);
            d2 = fmaf(xn[4 * cc + 2], v.z, d2);
            d3 = fmaf(xn[4 * cc + 3], v.w, d3);
        }
        float d = sqn + sqb[m] - 2.0f * ((d0 + d1) + (d2 + d3));
        unsigned bbits = __float_as_uint(d);
        unsigned sgn   = (unsigned)((int)bbits >> 31);
        unsigned u     = bbits ^ (sgn | 0x80000000u);  // total-order transform
        unsigned long long cur = ((unsigned long long)u << 32) | (unsigned)m;
#pragma unroll
        for (int s = 0; s < KNN; ++s) {
            unsigned long long lo = cur < best[s] ? cur : best[s];
            unsigned long long hi = cur < best[s] ? best[s] : cur;
            best[s] = lo; cur = hi;
        }
    }
#pragma unroll
    for (int k = 0; k < KNN; ++k) s_keys[sub][p][k] = best[k];
    __syncthreads();

    // 4-way merge of sorted 16-lists; keys unique (contain id) -> no ties
    if (t < 64) {
        int p0 = 0, p1 = 0, p2 = 0, p3 = 0;
#pragma unroll 1
        for (int k = 0; k < KNN; ++k) {
            unsigned long long bk = s_keys[0][t][p0]; int bq = 0;
            unsigned long long k1 = s_keys[1][t][p1]; if (k1 < bk) { bk = k1; bq = 1; }
            unsigned long long k2 = s_keys[2][t][p2]; if (k2 < bk) { bk = k2; bq = 2; }
            unsigned long long k3 = s_keys[3][t][p3]; if (k3 < bk) { bk = k3; bq = 3; }
            s_out[t][k] = (int)(bk & 0xFFFFu);
            if (bq == 0) ++p0; else if (bq == 1) ++p1; else if (bq == 2) ++p2; else ++p3;
        }
    }
    __syncthreads();

    // gather + max-pool: thread t -> point t>>2, 16 channels
    {
        int pp = t >> 2;
        int cg = (t & 3) * 16;
        size_t gp2 = (size_t)b * NN + n0 + pp;
        float acc[16];
#pragma unroll
        for (int i = 0; i < 16; ++i) acc[i] = -3.4e38f;
#pragma unroll 1
        for (int k = 0; k < KNN; ++k) {
            int idx = s_out[pp][k];
            const float4* src = (const float4*)(xb + (size_t)idx * CIN + cg);
#pragma unroll
            for (int j2 = 0; j2 < 4; ++j2) {
                float4 v = src[j2];
                acc[4 * j2 + 0] = fmaxf(acc[4 * j2 + 0], v.x);
                acc[4 * j2 + 1] = fmaxf(acc[4 * j2 + 1], v.y);
                acc[4 * j2 + 2] = fmaxf(acc[4 * j2 + 2], v.z);
                acc[4 * j2 + 3] = fmaxf(acc[4 * j2 + 3], v.w);
            }
        }
        float4* dst = (float4*)(pooled + gp2 * CIN + cg);
#pragma unroll
        for (int j2 = 0; j2 < 4; ++j2)
            dst[j2] = make_float4(acc[4 * j2 + 0], acc[4 * j2 + 1],
                                  acc[4 * j2 + 2], acc[4 * j2 + 3]);
    }
}

// ---------------------------------------------------------------------------
// Kernel 4: y = pooled @ W^T + b  (store y), accumulate per-channel sum/sumsq
// ---------------------------------------------------------------------------
__global__ __launch_bounds__(256) void gemm_stats_kernel(
    const float* __restrict__ pooled, const float* __restrict__ W,
    const float* __restrict__ bias, float* __restrict__ y, float* __restrict__ stats)
{
    __shared__ float sW[COUT * CIN];    // 32 KB
    __shared__ float sP[64 * CIN];      // 16 KB
    __shared__ float sred[256];

    size_t r0 = (size_t)blockIdx.x * 64;
    int t = threadIdx.x;

    for (int j = t; j < COUT * CIN / 4; j += 256)
        ((float4*)sW)[j] = ((const float4*)W)[j];
    for (int j = t; j < 64 * CIN / 4; j += 256)
        ((float4*)sP)[j] = ((const float4*)(pooled + r0 * CIN))[j];
    __syncthreads();

    int c = t & 127;                    // output channel
    int h = t >> 7;                     // row-half 0/1
    float wr[CIN];
#pragma unroll
    for (int k = 0; k < CIN; ++k) wr[k] = sW[c * CIN + k];
    float bc = bias[c];

    float lsum = 0.f, lsumsq = 0.f;
    for (int i = 0; i < 32; ++i) {
        int r = h * 32 + i;             // wave-uniform -> LDS broadcast
        float a0 = 0.f, a1 = 0.f, a2 = 0.f, a3 = 0.f;
#pragma unroll
        for (int k = 0; k < CIN; k += 4) {
            a0 = fmaf(wr[k + 0], sP[r * CIN + k + 0], a0);
            a1 = fmaf(wr[k + 1], sP[r * CIN + k + 1], a1);
            a2 = fmaf(wr[k + 2], sP[r * CIN + k + 2], a2);
            a3 = fmaf(wr[k + 3], sP[r * CIN + k + 3], a3);
        }
        float v = (a0 + a1) + (a2 + a3) + bc;
        y[(r0 + r) * COUT + c] = v;
        lsum += v; lsumsq = fmaf(v, v, lsumsq);
    }

    sred[t] = lsum; __syncthreads();
    if (h == 0) atomicAdd(&stats[c], sred[c] + sred[128 + c]);
    __syncthreads();
    sred[t] = lsumsq; __syncthreads();
    if (h == 0) atomicAdd(&stats[COUT + c], sred[c] + sred[128 + c]);
}

// ---------------------------------------------------------------------------
// Kernel 5: BatchNorm (population stats) + ReLU, float4 per thread
// ---------------------------------------------------------------------------
__global__ __launch_bounds__(256) void bn_relu_kernel(
    const float* __restrict__ y, const float* __restrict__ stats,
    const float* __restrict__ gamma, const float* __restrict__ beta,
    float* __restrict__ out)
{
    int i = blockIdx.x * 256 + threadIdx.x;            // float4 index
    float4 v = ((const float4*)y)[i];
    int c = (i * 4) & (COUT - 1);
    float r[4] = { v.x, v.y, v.z, v.w };
    float o[4];
    const float invM = 1.0f / (float)(BB * NN);
#pragma unroll
    for (int j = 0; j < 4; ++j) {
        int cc = c + j;
        float mean = stats[cc] * invM;
        float var  = stats[COUT + cc] * invM - mean * mean;
        float inv  = rsqrtf(var + 1e-5f);
        float val  = (r[j] - mean) * inv * gamma[cc] + beta[cc];
        o[j] = fmaxf(val, 0.0f);
    }
    ((float4*)out)[i] = make_float4(o[0], o[1], o[2], o[3]);
}

// ---------------------------------------------------------------------------
// ws layout (<= 24.5 MiB; 25 MiB known-safe):
//   [0, 128K)              sq (fp32, 32768)
//   [128K, 129K)           stats (sum[128], sumsq[128])
//   [256K, 256K+4M)        xh (fp16)
//   [4.5M, 10.5M)          sub_i (u16, 32768 x 96)
//   [256K, 256K+16M)       y (fp32) — aliases xh/sub_i (consumed by then)
//   [16.5M, 24.5M)         pooled (fp32)
// ---------------------------------------------------------------------------
extern "C" void kernel_launch(void* const* d_in, const int* in_sizes, int n_in,
                              void* d_out, int out_size, void* d_ws, size_t ws_size,
                              hipStream_t stream)
{
    const float* x     = (const float*)d_in[0];
    const float* W     = (const float*)d_in[1];
    const float* bias  = (const float*)d_in[2];
    const float* gamma = (const float*)d_in[3];
    const float* beta  = (const float*)d_in[4];
    float* out = (float*)d_out;

    char* ws = (char*)d_ws;
    float*          sq     = (float*)(ws);
    float*          stats  = (float*)(ws + 131072);
    _Float16*       xh     = (_Float16*)(ws + 262144);
    unsigned short* sub_i  = (unsigned short*)(ws + 4608u * 1024);
    float*          y      = (float*)(ws + 262144);
    float*          pooled = (float*)(ws + 16896u * 1024);

    hipLaunchKernelGGL(prep_kernel, dim3(BB * NN / 256), dim3(256), 0, stream,
                       x, sq, xh, stats);
    hipLaunchKernelGGL(knn_scan_mfma_kernel, dim3(BB * NN / 64 * 2), dim3(256), 0, stream,
                       xh, sq, sub_i);
    hipLaunchKernelGGL(rescue_pool_kernel, dim3(BB * NN / 64), dim3(256), 0, stream,
                       x, sq, sub_i, pooled);
    hipLaunchKernelGGL(gemm_stats_kernel, dim3(BB * NN / 64), dim3(256), 0, stream,
                       pooled, W, bias, y, stats);
    hipLaunchKernelGGL(bn_relu_kernel, dim3(BB * NN * COUT / (4 * 256)), dim3(256), 0, stream,
                       y, stats, gamma, beta, out);
}

// Round 5
// 289.798 us; speedup vs baseline: 3.1739x; 1.2353x over previous
//
#include <hip/hip_runtime.h>

#define BB   8
#define NN   4096
#define CIN  64
#define COUT 128
#define KNN  16
#define NSUB 12                       // approx top-12 per sublist, 8 sublists/point

typedef _Float16 half8 __attribute__((ext_vector_type(8)));
typedef float f32x4 __attribute__((ext_vector_type(4)));

// ---------------------------------------------------------------------------
// Kernel 1: fused per-point squared norm + fp32->fp16 conversion; block 0
// zeroes the BN stats accumulator. One thread per point.
// ---------------------------------------------------------------------------
__global__ __launch_bounds__(256) void prep_kernel(
    const float* __restrict__ x, float* __restrict__ sq,
    _Float16* __restrict__ xh, float* __restrict__ stats)
{
    int i = blockIdx.x * 256 + threadIdx.x;            // point id
    const float4* xr = (const float4*)(x + (size_t)i * CIN);
    half8* xw = (half8*)(xh + (size_t)i * CIN);
    float s0 = 0.f, s1 = 0.f;
#pragma unroll
    for (int j = 0; j < 8; ++j) {
        float4 a = xr[2 * j], b = xr[2 * j + 1];
        s0 = fmaf(a.x, a.x, s0); s0 = fmaf(a.y, a.y, s0);
        s0 = fmaf(a.z, a.z, s0); s0 = fmaf(a.w, a.w, s0);
        s1 = fmaf(b.x, b.x, s1); s1 = fmaf(b.y, b.y, s1);
        s1 = fmaf(b.z, b.z, s1); s1 = fmaf(b.w, b.w, s1);
        half8 h;
        h[0] = (_Float16)a.x; h[1] = (_Float16)a.y;
        h[2] = (_Float16)a.z; h[3] = (_Float16)a.w;
        h[4] = (_Float16)b.x; h[5] = (_Float16)b.y;
        h[6] = (_Float16)b.z; h[7] = (_Float16)b.w;
        xw[j] = h;
    }
    sq[i] = s0 + s1;
    if (blockIdx.x == 0) stats[threadIdx.x] = 0.0f;    // sum[128], sumsq[128]
}

// ---------------------------------------------------------------------------
// Kernel 2: MFMA kNN scan with packed-key selection (as R4) — now writes the
// FULL packed keys (trunc-dist | id, u32) so the rescue can rank the union
// without re-reading rows. 8 streams/point x sorted top-12 keys.
// ---------------------------------------------------------------------------
__global__ __launch_bounds__(256) void knn_scan_mfma_kernel(
    const _Float16* __restrict__ xh, const float* __restrict__ sq,
    unsigned* __restrict__ sub_k)
{
    __shared__ _Float16 sBT[8][64][8];   // 8 KB, [k-granule][cand][8 halfs]
    __shared__ unsigned s_key[64][68];   // 17 KB, [point][col], stride 68
    __shared__ float    s_sqn[64];
    __shared__ float    s_sqm[64];

    int blk  = blockIdx.x;
    int tile = blk >> 1;                 // 0..511
    int half = blk & 1;                  // candidate half (2048 each)
    int b    = tile >> 6;
    int n0   = (tile & 63) * 64;
    int t    = threadIdx.x;
    int l    = t & 63;                   // lane
    int w    = t >> 6;                   // wave id -> row strip 16w..16w+15
    int quad = (l >> 4);                 // 0..3
    int c16  = l & 15;

    const _Float16* xhb = xh + (size_t)b * NN * CIN;
    const float*    sqb = sq + (size_t)b * NN;

    if (t < 64) s_sqn[t] = sqb[n0 + t];

    // A fragments (query rows): A[m = 16w + c16][k = s*32 + quad*8 + j]
    int row_a = n0 + 16 * w + c16;
    half8 afrag0 = *(const half8*)(xhb + (size_t)row_a * CIN + 0 * 32 + quad * 8);
    half8 afrag1 = *(const half8*)(xhb + (size_t)row_a * CIN + 1 * 32 + quad * 8);

    // persistent approx top-12 packed keys, ascending
    unsigned best[NSUB];
#pragma unroll
    for (int j = 0; j < NSUB; ++j) best[j] = 0xFFFFFFFFu;

    int p = l;                           // selection: point index
    int q = w;                           // selection: col-strip id

    for (int c = 0; c < 32; ++c) {       // 32 chunks of 64 candidates
        int cbase = half * 2048 + c * 64;

        // stage candidate tile (64 rows x 64 halfs) granule-transposed
#pragma unroll
        for (int r = 0; r < 2; ++r) {
            int f = r * 256 + t;         // 16B-granule id, 0..511
            int cand = f >> 3;
            int g    = f & 7;
            *(half8*)&sBT[g][cand][0] =
                *(const half8*)(xhb + (size_t)(cbase + cand) * CIN + g * 8);
        }
        if (t < 64) s_sqm[t] = sqb[cbase + t];
        __syncthreads();

        // MFMA: wave w computes rows [16w,16w+16) x all 64 cols (4 subtiles)
        f32x4 acc[4];
#pragma unroll
        for (int n = 0; n < 4; ++n) { acc[n] = (f32x4){0.f, 0.f, 0.f, 0.f}; }
#pragma unroll
        for (int n = 0; n < 4; ++n) {
            half8 b0 = *(const half8*)&sBT[0 * 4 + quad][16 * n + c16][0];
            half8 b1 = *(const half8*)&sBT[1 * 4 + quad][16 * n + c16][0];
            acc[n] = __builtin_amdgcn_mfma_f32_16x16x32_f16(afrag0, b0, acc[n], 0, 0, 0);
            acc[n] = __builtin_amdgcn_mfma_f32_16x16x32_f16(afrag1, b1, acc[n], 0, 0, 0);
        }

        // epilogue: dist = max(sqn + sqm - 2*dot, 0); pack key; write [row][col]
#pragma unroll
        for (int n = 0; n < 4; ++n) {
            int col = 16 * n + c16;
            float sm = s_sqm[col];
            unsigned id = (unsigned)(cbase + col);
#pragma unroll
            for (int r = 0; r < 4; ++r) {
                int row = 16 * w + quad * 4 + r;
                float d = fmaxf(s_sqn[row] + sm - 2.0f * acc[n][r], 0.0f);
                s_key[row][col] = (__float_as_uint(d) & 0xFFFFF000u) | id;
            }
        }
        __syncthreads();

        // selection: thread (p, q) scans cols q*16..q*16+15, b128 key reads,
        // unconditional compare-exchange insert (2 instr/stage)
#pragma unroll
        for (int j = 0; j < 4; ++j) {
            uint4 kv = *(const uint4*)&s_key[p][q * 16 + 4 * j];
            unsigned kk[4] = { kv.x, kv.y, kv.z, kv.w };
#pragma unroll
            for (int e = 0; e < 4; ++e) {
                unsigned cur = kk[e];
#pragma unroll
                for (int s = 0; s < NSUB; ++s) {
                    unsigned lo = min(best[s], cur);
                    unsigned hi = max(best[s], cur);
                    best[s] = lo; cur = hi;
                }
            }
        }
        __syncthreads();                 // protect s_key/sBT before next chunk
    }

    // write sorted key sublist: [point][half*4+q][12], 3x uint4 stores
    size_t base = (((size_t)b * NN + n0 + p) * 8 + half * 4 + q) * NSUB;
    uint4* dst = (uint4*)(sub_k + base);
    dst[0] = make_uint4(best[0], best[1], best[2],  best[3]);
    dst[1] = make_uint4(best[4], best[5], best[6],  best[7]);
    dst[2] = make_uint4(best[8], best[9], best[10], best[11]);
}

// ---------------------------------------------------------------------------
// Kernel 3: rescue + gather + max-pool, key-pruned.
// Block = 64 points, 4 threads/point (p = t&63, sub = t>>6).
//  P1: thread CEs its 24 approx keys (2 scan streams) -> sorted top-16.
//      (P(2 of 8 streams hold >=16 of true top-16) ~ 2e-10 -> union-64 covers)
//  P2: 4-way merge -> top-24 candidate ids by approx rank (true top-16 rank
//      <= 16 + key-error window << 24 whp).
//  P3: exact fp32 distances for 6 ids/thread; 64-bit reference-faithful keys
//      ((sign-fixed dist bits)<<32 | id, smaller-id-wins ties); sorted-6 CE.
//  P4: 4-way merge -> exact top-16 set; gather rows (L1/L2 hot) + max-pool.
// Row traffic: 24+16 rows/point vs 96+16 in R4 -> ~2.6x fewer bytes, 4x fewer
// scattered line transactions.
// ---------------------------------------------------------------------------
__global__ __launch_bounds__(256) void rescue_pool_kernel(
    const float* __restrict__ x, const float* __restrict__ sq,
    const unsigned* __restrict__ sub_k, float* __restrict__ pooled)
{
    __shared__ unsigned s_pk[4][64][17];            // 17.4 KB sorted top-16 + pad
    __shared__ unsigned short s_cand[64][26];       // 3.3 KB 24 ids + pad
    __shared__ unsigned long long s_ek[4][64][6];   // 12 KB sorted-6 exact keys
    __shared__ int s_out[64][KNN];                  // 4 KB

    int blk = blockIdx.x;
    int b   = blk >> 6;
    int n0  = (blk & 63) * 64;
    int t   = threadIdx.x;
    int p   = t & 63;
    int sub = t >> 6;
    const float* xb  = x  + (size_t)b * NN * CIN;
    const float* sqb = sq + (size_t)b * NN;
    size_t gp = (size_t)b * NN + n0 + p;

    // query row in registers (4x redundant per point; L1-hot)
    float xn[CIN];
    {
        const float4* xr = (const float4*)(xb + (size_t)(n0 + p) * CIN);
#pragma unroll
        for (int j = 0; j < CIN / 4; ++j) {
            float4 v = xr[j];
            xn[4 * j + 0] = v.x; xn[4 * j + 1] = v.y;
            xn[4 * j + 2] = v.z; xn[4 * j + 3] = v.w;
        }
    }
    float sqn = sqb[n0 + p];

    // P1: CE 24 keys -> sorted top-16
    {
        unsigned bk[16];
#pragma unroll
        for (int j = 0; j < 16; ++j) bk[j] = 0xFFFFFFFFu;
        const uint4* kp = (const uint4*)(sub_k + gp * 96 + sub * 24);
#pragma unroll
        for (int j = 0; j < 6; ++j) {
            uint4 kv = kp[j];
            unsigned kk[4] = { kv.x, kv.y, kv.z, kv.w };
#pragma unroll
            for (int e = 0; e < 4; ++e) {
                unsigned cur = kk[e];
#pragma unroll
                for (int s = 0; s < 16; ++s) {
                    unsigned lo = min(bk[s], cur);
                    unsigned hi = max(bk[s], cur);
                    bk[s] = lo; cur = hi;
                }
            }
        }
#pragma unroll
        for (int j = 0; j < 16; ++j) s_pk[sub][p][j] = bk[j];
    }
    __syncthreads();

    // P2: 4-way merge of sorted-16 key lists -> top-24 ids
    if (t < 64) {
        int p0 = 0, p1 = 0, p2 = 0, p3 = 0;
#pragma unroll 1
        for (int k = 0; k < 24; ++k) {
            unsigned k0 = (p0 < 16) ? s_pk[0][t][p0] : 0xFFFFFFFFu;
            unsigned k1 = (p1 < 16) ? s_pk[1][t][p1] : 0xFFFFFFFFu;
            unsigned k2 = (p2 < 16) ? s_pk[2][t][p2] : 0xFFFFFFFFu;
            unsigned k3 = (p3 < 16) ? s_pk[3][t][p3] : 0xFFFFFFFFu;
            unsigned bk = k0; int bq = 0;
            if (k1 < bk) { bk = k1; bq = 1; }
            if (k2 < bk) { bk = k2; bq = 2; }
            if (k3 < bk) { bk = k3; bq = 3; }
            s_cand[t][k] = (unsigned short)(bk & 0xFFFu);
            if (bq == 0) ++p0; else if (bq == 1) ++p1; else if (bq == 2) ++p2; else ++p3;
        }
    }
    __syncthreads();

    // P3: exact fp32 distance for 6 candidates, sorted-6 via 64-bit CE
    {
        unsigned long long b6[6];
#pragma unroll
        for (int j = 0; j < 6; ++j) b6[j] = ~0ULL;
#pragma unroll 1
        for (int j = 0; j < 6; ++j) {
            int m = s_cand[p][sub * 6 + j];
            const float4* xm4 = (const float4*)(xb + (size_t)m * CIN);
            float d0 = 0.f, d1 = 0.f, d2 = 0.f, d3 = 0.f;
#pragma unroll
            for (int cc = 0; cc < CIN / 4; ++cc) {
                float4 v = xm4[cc];
                d0 = fmaf(xn[4 * cc + 0], v.x, d0);
                d1 = fmaf(xn[4 * cc + 1], v.y, d1);
                d2 = fmaf(xn[4 * cc + 2], v.z, d2);
                d3 = fmaf(xn[4 * cc + 3], v.w, d3);
            }
            float d = sqn + sqb[m] - 2.0f * ((d0 + d1) + (d2 + d3));
            unsigned bbits = __float_as_uint(d);
            unsigned sgn   = (unsigned)((int)bbits >> 31);
            unsigned u     = bbits ^ (sgn | 0x80000000u);  // total-order transform
            unsigned long long cur = ((unsigned long long)u << 32) | (unsigned)m;
#pragma unroll
            for (int s = 0; s < 6; ++s) {
                unsigned long long lo = cur < b6[s] ? cur : b6[s];
                unsigned long long hi = cur < b6[s] ? b6[s] : cur;
                b6[s] = lo; cur = hi;
            }
        }
#pragma unroll
        for (int j = 0; j < 6; ++j) s_ek[sub][p][j] = b6[j];
    }
    __syncthreads();

    // P4a: 4-way merge sorted-6 exact-key lists -> exact top-16 ids
    if (t < 64) {
        int p0 = 0, p1 = 0, p2 = 0, p3 = 0;
#pragma unroll 1
        for (int k = 0; k < KNN; ++k) {
            unsigned long long k0 = (p0 < 6) ? s_ek[0][t][p0] : ~0ULL;
            unsigned long long k1 = (p1 < 6) ? s_ek[1][t][p1] : ~0ULL;
            unsigned long long k2 = (p2 < 6) ? s_ek[2][t][p2] : ~0ULL;
            unsigned long long k3 = (p3 < 6) ? s_ek[3][t][p3] : ~0ULL;
            unsigned long long bk = k0; int bq = 0;
            if (k1 < bk) { bk = k1; bq = 1; }
            if (k2 < bk) { bk = k2; bq = 2; }
            if (k3 < bk) { bk = k3; bq = 3; }
            s_out[t][k] = (int)(bk & 0xFFFu);
            if (bq == 0) ++p0; else if (bq == 1) ++p1; else if (bq == 2) ++p2; else ++p3;
        }
    }
    __syncthreads();

    // P4b: gather + max-pool: thread t -> point t>>2, 16 channels
    {
        int pp = t >> 2;
        int cg = (t & 3) * 16;
        size_t gp2 = (size_t)b * NN + n0 + pp;
        float acc[16];
#pragma unroll
        for (int i = 0; i < 16; ++i) acc[i] = -3.4e38f;
#pragma unroll 1
        for (int k = 0; k < KNN; ++k) {
            int idx = s_out[pp][k];
            const float4* src = (const float4*)(xb + (size_t)idx * CIN + cg);
#pragma unroll
            for (int j2 = 0; j2 < 4; ++j2) {
                float4 v = src[j2];
                acc[4 * j2 + 0] = fmaxf(acc[4 * j2 + 0], v.x);
                acc[4 * j2 + 1] = fmaxf(acc[4 * j2 + 1], v.y);
                acc[4 * j2 + 2] = fmaxf(acc[4 * j2 + 2], v.z);
                acc[4 * j2 + 3] = fmaxf(acc[4 * j2 + 3], v.w);
            }
        }
        float4* dst = (float4*)(pooled + gp2 * CIN + cg);
#pragma unroll
        for (int j2 = 0; j2 < 4; ++j2)
            dst[j2] = make_float4(acc[4 * j2 + 0], acc[4 * j2 + 1],
                                  acc[4 * j2 + 2], acc[4 * j2 + 3]);
    }
}

// ---------------------------------------------------------------------------
// Kernel 4: y = pooled @ W^T + b  (store y), accumulate per-channel sum/sumsq
// ---------------------------------------------------------------------------
__global__ __launch_bounds__(256) void gemm_stats_kernel(
    const float* __restrict__ pooled, const float* __restrict__ W,
    const float* __restrict__ bias, float* __restrict__ y, float* __restrict__ stats)
{
    __shared__ float sW[COUT * CIN];    // 32 KB
    __shared__ float sP[64 * CIN];      // 16 KB
    __shared__ float sred[256];

    size_t r0 = (size_t)blockIdx.x * 64;
    int t = threadIdx.x;

    for (int j = t; j < COUT * CIN / 4; j += 256)
        ((float4*)sW)[j] = ((const float4*)W)[j];
    for (int j = t; j < 64 * CIN / 4; j += 256)
        ((float4*)sP)[j] = ((const float4*)(pooled + r0 * CIN))[j];
    __syncthreads();

    int c = t & 127;                    // output channel
    int h = t >> 7;                     // row-half 0/1
    float wr[CIN];
#pragma unroll
    for (int k = 0; k < CIN; ++k) wr[k] = sW[c * CIN + k];
    float bc = bias[c];

    float lsum = 0.f, lsumsq = 0.f;
    for (int i = 0; i < 32; ++i) {
        int r = h * 32 + i;             // wave-uniform -> LDS broadcast
        float a0 = 0.f, a1 = 0.f, a2 = 0.f, a3 = 0.f;
#pragma unroll
        for (int k = 0; k < CIN; k += 4) {
            a0 = fmaf(wr[k + 0], sP[r * CIN + k + 0], a0);
            a1 = fmaf(wr[k + 1], sP[r * CIN + k + 1], a1);
            a2 = fmaf(wr[k + 2], sP[r * CIN + k + 2], a2);
            a3 = fmaf(wr[k + 3], sP[r * CIN + k + 3], a3);
        }
        float v = (a0 + a1) + (a2 + a3) + bc;
        y[(r0 + r) * COUT + c] = v;
        lsum += v; lsumsq = fmaf(v, v, lsumsq);
    }

    sred[t] = lsum; __syncthreads();
    if (h == 0) atomicAdd(&stats[c], sred[c] + sred[128 + c]);
    __syncthreads();
    sred[t] = lsumsq; __syncthreads();
    if (h == 0) atomicAdd(&stats[COUT + c], sred[c] + sred[128 + c]);
}

// ---------------------------------------------------------------------------
// Kernel 5: BatchNorm (population stats) + ReLU, float4 per thread
// ---------------------------------------------------------------------------
__global__ __launch_bounds__(256) void bn_relu_kernel(
    const float* __restrict__ y, const float* __restrict__ stats,
    const float* __restrict__ gamma, const float* __restrict__ beta,
    float* __restrict__ out)
{
    int i = blockIdx.x * 256 + threadIdx.x;            // float4 index
    float4 v = ((const float4*)y)[i];
    int c = (i * 4) & (COUT - 1);
    float r[4] = { v.x, v.y, v.z, v.w };
    float o[4];
    const float invM = 1.0f / (float)(BB * NN);
#pragma unroll
    for (int j = 0; j < 4; ++j) {
        int cc = c + j;
        float mean = stats[cc] * invM;
        float var  = stats[COUT + cc] * invM - mean * mean;
        float inv  = rsqrtf(var + 1e-5f);
        float val  = (r[j] - mean) * inv * gamma[cc] + beta[cc];
        o[j] = fmaxf(val, 0.0f);
    }
    ((float4*)out)[i] = make_float4(o[0], o[1], o[2], o[3]);
}

// ---------------------------------------------------------------------------
// ws layout (25 MiB exactly; known-safe):
//   [0, 128K)          sq (fp32)
//   [128K, 129K)       stats (sum[128], sumsq[128])
//   [256K, 4.25M)      xh (fp16, 4 MB)
//   [4.25M, 16.83M)    sub_k (u32, 32768 x 96 = 12.6 MB)
//   [256K, 16.25M)     y (fp32, 16 MB) — aliases xh/sub_k (consumed first)
//   [17M, 25M)         pooled (fp32, 8 MB)
// ---------------------------------------------------------------------------
extern "C" void kernel_launch(void* const* d_in, const int* in_sizes, int n_in,
                              void* d_out, int out_size, void* d_ws, size_t ws_size,
                              hipStream_t stream)
{
    const float* x     = (const float*)d_in[0];
    const float* W     = (const float*)d_in[1];
    const float* bias  = (const float*)d_in[2];
    const float* gamma = (const float*)d_in[3];
    const float* beta  = (const float*)d_in[4];
    float* out = (float*)d_out;

    char* ws = (char*)d_ws;
    float*     sq     = (float*)(ws);
    float*     stats  = (float*)(ws + 131072);
    _Float16*  xh     = (_Float16*)(ws + 262144);
    unsigned*  sub_k  = (unsigned*)(ws + 262144 + 4u * 1024 * 1024);
    float*     y      = (float*)(ws + 262144);
    float*     pooled = (float*)(ws + 17u * 1024 * 1024);

    hipLaunchKernelGGL(prep_kernel, dim3(BB * NN / 256), dim3(256), 0, stream,
                       x, sq, xh, stats);
    hipLaunchKernelGGL(knn_scan_mfma_kernel, dim3(BB * NN / 64 * 2), dim3(256), 0, stream,
                       xh, sq, sub_k);
    hipLaunchKernelGGL(rescue_pool_kernel, dim3(BB * NN / 64), dim3(256), 0, stream,
                       x, sq, sub_k, pooled);
    hipLaunchKernelGGL(gemm_stats_kernel, dim3(BB * NN / 64), dim3(256), 0, stream,
                       pooled, W, bias, y, stats);
    hipLaunchKernelGGL(bn_relu_kernel, dim3(BB * NN * COUT / (4 * 256)), dim3(256), 0, stream,
                       y, stats, gamma, beta, out);
}